// Round 16
// baseline (75.519 us; speedup 1.0000x reference)
//
#include <hip/hip_runtime.h>

#define LPOS 256
#define CCH 20
#define BB 4096
#define LC 5120   // LPOS*CCH

// seqC layout: uint4[16][4096] — entry (mw, b) holds bytes s(b, l=16mw..16mw+15).

// ---------------- Kernel 1: seq extraction + linear term -------------------
__global__ __launch_bounds__(256) void k_prepare(
    const float* __restrict__ x_lc, const float* __restrict__ theta_0,
    const float* __restrict__ theta_lc, unsigned char* __restrict__ seqC,
    float* __restrict__ out)
{
    const int b = blockIdx.x;
    const int l = threadIdx.x;
    const float* xp = x_lc + (size_t)b * LC + (size_t)l * CCH;
    const float4* xp4 = reinterpret_cast<const float4*>(xp);
    float v[CCH];
#pragma unroll
    for (int q = 0; q < 5; ++q) {
        float4 t = xp4[q];
        v[q * 4 + 0] = t.x; v[q * 4 + 1] = t.y;
        v[q * 4 + 2] = t.z; v[q * 4 + 3] = t.w;
    }
    int s = 0; float best = v[0];
#pragma unroll
    for (int c = 1; c < CCH; ++c) { if (v[c] > best) { best = v[c]; s = c; } }

    seqC[(size_t)(l >> 4) * (BB * 16) + (size_t)b * 16 + (l & 15)] =
        (unsigned char)s;

    float lin = theta_lc[l * CCH + s];
#pragma unroll
    for (int off = 32; off > 0; off >>= 1) lin += __shfl_down(lin, off, 64);
    __shared__ float partial[4];
    const int wave = threadIdx.x >> 6;
    const int lane = threadIdx.x & 63;
    if (lane == 0) partial[wave] = lin;
    __syncthreads();
    if (threadIdx.x == 0)
        out[b] = theta_0[0] + partial[0] + partial[1] + partial[2] + partial[3];
}

// ---------------- Kernel 2: masked pairwise quadratic form -----------------
// quad[b] = sum_{l1<l2} Theta[l1,s1,l2,s2]. Flat list of 2160 16-wide
// l2-chunks. 1024 blocks (4/CU x 8 waves, single generation): every block
// takes 2 chunks (positions 2*blk of the first 2048); the 112 leftover
// chunks (positions 2048..2159) are split into 448 FOUR-wide quarter-chunks,
// one each for blocks 0..447 (R15 lesson: 3-vs-2 full chunks made a 112-CU
// straggler tail at 1 block/CU; quarters cut heavy-block surplus 50%->12.5%).
// Per chunk: 16x20x20 f32 table (25 1KB gload_lds segments) staged once,
// then all 4096 batches gathered (thread t: batches i*512+t, i<8).
#define QT 512
#define TBL 6400              // 16*20*20 f32 = 25600 B, 1600 quads, 25 segs
#define NCHT 2160             // total 16-wide chunks
#define NBLK 1024
#define NQEXT 448             // blocks carrying a 4-wide quarter-chunk

template <int MODE>
__global__ __launch_bounds__(QT, 8) void k_quad(
    const float* __restrict__ Theta,          // (5120, 5120) f32 row-major
    const uint4* __restrict__ seqC,           // [16][4096]
    float* __restrict__ part,                 // [NBLK][4096] (MODE 0)
    float* __restrict__ out)                  // (MODE 1)
{
    __shared__ float Tl[TBL];    // 25.6 KB -> 4 blocks/CU (102.4 KB)

    const int blk = blockIdx.x;
    const int tid = threadIdx.x;
    const int wave = tid >> 6;
    const int lane = tid & 63;

    // ---- locate chunks 2*blk, 2*blk+1 in the flat list (scalar walk) ----
    int cl1[2], cm[2], cjl[2];
    {
        int T = 2 * blk, l1 = 0;
        for (; l1 < 255; ++l1) {
            const int c = 16 - ((l1 + 1) >> 4);
            if (T < c) break;
            T -= c;
        }
        int m = ((l1 + 1) >> 4) + T;
#pragma unroll
        for (int d = 0; d < 2; ++d) {
            cl1[d] = l1; cm[d] = m;
            cjl[d] = (m == ((l1 + 1) >> 4)) ? ((l1 + 1) & 15) : 0;
            ++m;
            if (m == 16) { ++l1; m = (l1 + 1) >> 4; }
        }
    }
    // ---- quarter-chunk (blocks 0..447): flat pos 2048 + blk/4, sub blk%4 --
    int ql1 = 0, qm = 0, qjl = 0;
    const int qsub = blk & 3;
    if (blk < NQEXT) {
        int T = 2048 + (blk >> 2), l1 = 0;
        for (; l1 < 255; ++l1) {
            const int c = 16 - ((l1 + 1) >> 4);
            if (T < c) break;
            T -= c;
        }
        ql1 = l1;
        qm = ((l1 + 1) >> 4) + T;
        qjl = (qm == ((l1 + 1) >> 4)) ? ((l1 + 1) & 15) : 0;
    }

    // Stage 16-wide chunk (l1, m): quad u = seg*64+lane (< 1600 exactly) ->
    // elems 4u..4u+3; r = u/5 (= j*20+s1), cc = u%5 -> Theta row l1*20+s1,
    // cols (16m+j)*20 + 4cc..+3 (16B-aligned, in-row).
    auto stage = [&](int l1, int m) {
#pragma unroll
        for (int k = 0; k < 4; ++k) {
            const int seg = wave + 8 * k;
            if (seg < 25) {
                const int u = seg * 64 + lane;
                const int r = u / 5, cc = u - r * 5;
                const int j = r / CCH, s1 = r - j * CCH;
                const float* gp = Theta + (size_t)(l1 * CCH + s1) * LC
                                        + (m * 16 + j) * CCH + cc * 4;
                float* lp = Tl + seg * 256;
                __builtin_amdgcn_global_load_lds(
                    (const __attribute__((address_space(1))) void*)gp,
                    (__attribute__((address_space(3))) void*)lp, 16, 0, 0);
            }
        }
    };
    // Stage 4-wide quarter (ql1, qm, qsub): 400 quads, 7 segs, clamp pad.
    // Table layout [j][s1][s2], j in [0,4): global col (16qm + 4qsub + j)*20
    // + 4cc..+3. Dest linear; quads past 399 hold dup data (never read).
    auto stage_q = [&]() {
        const int seg = wave;            // 8 waves, segs 0..6 active
        if (seg < 7) {
            const int u0 = seg * 64 + lane;
            const int u = (u0 < 400) ? u0 : 399;
            const int r = u / 5, cc = u - r * 5;
            const int j = r / CCH, s1 = r - j * CCH;
            const float* gp = Theta + (size_t)(ql1 * CCH + s1) * LC
                                    + (qm * 16 + qsub * 4 + j) * CCH + cc * 4;
            float* lp = Tl + seg * 256;
            __builtin_amdgcn_global_load_lds(
                (const __attribute__((address_space(1))) void*)gp,
                (__attribute__((address_space(3))) void*)lp, 16, 0, 0);
        }
    };
    // basev[i] = s1(b_i, l1) * 20 from byte (l1&15) of seqC[l1>>4][b_i]
    int basev[8];
    auto loadbase = [&](int l1) {
        const int mw = l1 >> 4;
        const int wsel = (l1 >> 2) & 3;
        const int sh = (l1 & 3) * 8;
#pragma unroll
        for (int i = 0; i < 8; ++i) {
            const uint4 u = seqC[(size_t)mw * BB + i * QT + tid];
            const unsigned w = (wsel == 0) ? u.x : (wsel == 1) ? u.y
                             : (wsel == 2) ? u.z : u.w;
            basev[i] = (int)((w >> sh) & 0xFFu) * CCH;
        }
    };

    float acc[8];
#pragma unroll
    for (int i = 0; i < 8; ++i) acc[i] = 0.f;

    // gather one 16-wide chunk d
    auto gather = [&](int d) {
        const int jl = cjl[d];
        const size_t mrow = (size_t)cm[d] * BB;
        if (jl == 0) {
#pragma unroll
            for (int i = 0; i < 8; ++i) {
                const uint4 u = seqC[mrow + i * QT + tid];   // inline, 1 live
#pragma unroll
                for (int j = 0; j < 16; ++j) {
                    const unsigned w = (j < 4) ? u.x : (j < 8) ? u.y
                                     : (j < 12) ? u.z : u.w;
                    const int s2 = (w >> ((j & 3) * 8)) & 0xFF;
                    acc[i] += Tl[j * 400 + basev[i] + s2];
                }
            }
        } else {            // ragged first chunk of a row (uniform jl)
#pragma unroll
            for (int i = 0; i < 8; ++i) {
                const uint4 u = seqC[mrow + i * QT + tid];
#pragma unroll
                for (int j = 0; j < 16; ++j) {
                    const unsigned w = (j < 4) ? u.x : (j < 8) ? u.y
                                     : (j < 12) ? u.z : u.w;
                    const int s2 = (w >> ((j & 3) * 8)) & 0xFF;
                    const float v = Tl[j * 400 + basev[i] + s2];
                    acc[i] += (j >= jl) ? v : 0.f;
                }
            }
        }
    };

    // ---- chunk 0 ----
    stage(cl1[0], cm[0]);
    loadbase(cl1[0]);
    __syncthreads();            // table ready
    gather(0);
    // ---- chunk 1 ----
    __syncthreads();            // WAR: reads done before restage
    stage(cl1[1], cm[1]);
    if (cl1[1] != cl1[0]) loadbase(cl1[1]);
    __syncthreads();            // table ready
    gather(1);
    // ---- quarter chunk (blocks 0..447) ----
    if (blk < NQEXT) {
        __syncthreads();        // WAR
        stage_q();
        if (ql1 != cl1[1]) loadbase(ql1);
        __syncthreads();        // table ready
        const size_t mrow = (size_t)qm * BB;
#pragma unroll
        for (int i = 0; i < 8; ++i) {
            const uint4 u = seqC[mrow + i * QT + tid];
            const unsigned w = (qsub == 0) ? u.x : (qsub == 1) ? u.y
                             : (qsub == 2) ? u.z : u.w;
#pragma unroll
            for (int j = 0; j < 4; ++j) {
                const int s2 = (w >> (j * 8)) & 0xFF;
                const float v = Tl[j * 400 + basev[i] + s2];
                const int jj = qsub * 4 + j;
                acc[i] += (jj >= qjl) ? v : 0.f;
            }
        }
    }

    if (MODE == 0) {
        float* row = part + (size_t)blk * BB;
#pragma unroll
        for (int i = 0; i < 8; ++i) row[i * QT + tid] = acc[i];
    } else {
#pragma unroll
        for (int i = 0; i < 8; ++i) atomicAdd(&out[i * QT + tid], acc[i]);
    }
}

// ---------------- Kernel 3: reduce partial rows into out -------------------
// grid (4, 64): x -> 256 float4-columns of out, y -> 16 part rows each.
__global__ __launch_bounds__(256) void k_reduce(
    const float4* __restrict__ part4,   // [NBLK][1024]
    float* __restrict__ out)
{
    const int b4 = blockIdx.x * 256 + threadIdx.x;   // < 1024
    const int r0 = blockIdx.y * 16;
    float4 a = make_float4(0.f, 0.f, 0.f, 0.f);
    for (int r = r0; r < r0 + 16; ++r) {
        const float4 p = part4[(size_t)r * 1024 + b4];
        a.x += p.x; a.y += p.y; a.z += p.z; a.w += p.w;
    }
    atomicAdd(&out[b4 * 4 + 0], a.x);
    atomicAdd(&out[b4 * 4 + 1], a.y);
    atomicAdd(&out[b4 * 4 + 2], a.z);
    atomicAdd(&out[b4 * 4 + 3], a.w);
}

extern "C" void kernel_launch(void* const* d_in, const int* in_sizes, int n_in,
                              void* d_out, int out_size, void* d_ws, size_t ws_size,
                              hipStream_t stream) {
    const float* x_lc       = (const float*)d_in[0];
    const float* theta_0    = (const float*)d_in[1];
    const float* theta_lc   = (const float*)d_in[2];
    const float* theta_lclc = (const float*)d_in[3];
    // d_in[4] = mask (bool) — implicit: we only iterate l2 > l1.
    float* out = (float*)d_out;

    unsigned char* seqC = (unsigned char*)d_ws;            // 1 MB
    float* part = (float*)((char*)d_ws + (1 << 20));       // 16.8 MB
    const size_t need = (1 << 20) + (size_t)NBLK * BB * 4;

    k_prepare<<<dim3(BB), dim3(256), 0, stream>>>(x_lc, theta_0, theta_lc, seqC, out);
    if (ws_size >= need) {
        k_quad<0><<<dim3(NBLK), dim3(QT), 0, stream>>>(
            theta_lclc, (const uint4*)seqC, part, out);
        k_reduce<<<dim3(4, 64), dim3(256), 0, stream>>>(
            (const float4*)part, out);
    } else {
        k_quad<1><<<dim3(NBLK), dim3(QT), 0, stream>>>(
            theta_lclc, (const uint4*)seqC, part, out);
    }
}